// Round 20
// baseline (448.877 us; speedup 1.0000x reference)
//
#include <hip/hip_runtime.h>

// Problem constants (fixed by the reference)
#define N2 2048
#define NNZ 32768
#define LK 22          // FROZEN: absmax 0.0234 of 0.037 threshold (3 of ~4.7 bf16 ulps)
#define NBL 128        // lanczos grid blocks: 128 x 512 thr; 147KB LDS -> 1 block/CU
#define BINCAP 64      // slots per bin (Poisson(16) tail ~1e-15)

typedef __attribute__((ext_vector_type(8))) _Float16 half8;
typedef __attribute__((ext_vector_type(4))) float f32x4;

#define AGENT __HIP_MEMORY_SCOPE_AGENT
#define AS1C(p) ((const __attribute__((address_space(1))) unsigned int*)(p))
#define AS3(p)  ((__attribute__((address_space(3))) unsigned int*)(p))

__device__ __forceinline__ unsigned short f2h(float f) {
  _Float16 h = (_Float16)f;                   // fp16 RNE
  return *(unsigned short*)&h;
}

// ==== R35: MEASUREMENT ROUND (in-kernel reps=8, idempotent bodies).
// Ten rounds of split-inference produced one real win (R6 fp16) and five
// nulls on gemmM levers; the 48us gemmM attribution is unverified. reps=8
// pushes gatherG/gemmM dispatch durations past lanczos' 125us IFF their
// single-shot cost > ~16us -> they surface in rocprof top-5 WITH counters.
// Same launch count as R19 (no duplicated dispatches).

// ---- 1. W (fp32) -> fp16; zero row/col bin counters ----
__global__ __launch_bounds__(256) void convert_kernel(const float* __restrict__ W,
                                                      unsigned short* __restrict__ Hf,
                                                      unsigned* __restrict__ cntR,
                                                      unsigned* __restrict__ cntC) {
  if (blockIdx.x < 8)       cntR[blockIdx.x * 256 + threadIdx.x] = 0;
  else if (blockIdx.x < 16) cntC[(blockIdx.x - 8) * 256 + threadIdx.x] = 0;
  int i4 = blockIdx.x * 256 + threadIdx.x;          // grid 4096 -> 1048576 float4s
  float4 w = ((const float4*)W)[i4];
  ushort4 h;
  h.x = f2h(w.x); h.y = f2h(w.y); h.z = f2h(w.z); h.w = f2h(w.w);
  ((ushort4*)Hf)[i4] = h;
}

// ---- 2. fill row bins (G-gather, SS^T) and column bins (S^T, SS^T) ----
__global__ __launch_bounds__(256) void fill_kernel(const float* __restrict__ pred,
                                                   const float* __restrict__ scal,
                                                   const int* __restrict__ rows,
                                                   const int* __restrict__ cols,
                                                   unsigned* __restrict__ cntR,
                                                   int* __restrict__ binRc,
                                                   float* __restrict__ binRv,
                                                   unsigned* __restrict__ cntC,
                                                   int* __restrict__ binCr,
                                                   float* __restrict__ binCv) {
  int k = blockIdx.x * 256 + threadIdx.x;
  int r = rows[k], c = cols[k];
  float v = pred[k] * scal[k];
  unsigned pR = atomicAdd(&cntR[r], 1u);
  if (pR < BINCAP) { binRc[r * BINCAP + pR] = c; binRv[r * BINCAP + pR] = v; }
  unsigned pC = atomicAdd(&cntC[c], 1u);
  if (pC < BINCAP) { binCr[c * BINCAP + pC] = r; binCv[c * BINCAP + pC] = v; }
}

// ---- 3. G[r,:] = Hf[r,:] + sum_e v_e * Hf[c_e,:]  (fp16 out, fp32 acc, MLP-8)
//      R35: reps loop (idempotent; bins hoisted; no LDS hazard) ----
__global__ __launch_bounds__(256) void gatherG_kernel(const unsigned* __restrict__ cntR,
                                                      const int* __restrict__ binRc,
                                                      const float* __restrict__ binRv,
                                                      const unsigned short* __restrict__ Hf,
                                                      unsigned short* __restrict__ Gh,
                                                      int reps) {
  const int r = blockIdx.x, tid = threadIdx.x;
  __shared__ int scol_[BINCAP];
  __shared__ float sval_[BINCAP];
  const unsigned ne = min(cntR[r], (unsigned)BINCAP);
  if (tid < ne) {
    scol_[tid] = binRc[r * BINCAP + tid];
    sval_[tid] = binRv[r * BINCAP + tid];
  }
  __syncthreads();
  for (int rep = 0; rep < reps; ++rep) {
    // init from own row (the I in L = I + S)
    uint4 own = *(const uint4*)(Hf + (size_t)r * 2048 + tid * 8);
    half8 ho = *(half8*)&own;
    float acc[8];
#pragma unroll
    for (int k = 0; k < 8; ++k) acc[k] = (float)ho[k];
    unsigned e = 0;
    for (; e + 8 <= ne; e += 8) {
      uint4 q[8];
#pragma unroll
      for (int u = 0; u < 8; ++u)
        q[u] = *(const uint4*)(Hf + (size_t)scol_[e + u] * 2048 + tid * 8);
#pragma unroll
      for (int u = 0; u < 8; ++u) {
        half8 hv = *(half8*)&q[u];
        const float v = sval_[e + u];
#pragma unroll
        for (int k = 0; k < 8; ++k) acc[k] += v * (float)hv[k];
      }
    }
    for (; e + 4 <= ne; e += 4) {
      uint4 q[4];
#pragma unroll
      for (int u = 0; u < 4; ++u)
        q[u] = *(const uint4*)(Hf + (size_t)scol_[e + u] * 2048 + tid * 8);
#pragma unroll
      for (int u = 0; u < 4; ++u) {
        half8 hv = *(half8*)&q[u];
        const float v = sval_[e + u];
#pragma unroll
        for (int k = 0; k < 8; ++k) acc[k] += v * (float)hv[k];
      }
    }
    for (; e < ne; ++e) {
      uint4 qq = *(const uint4*)(Hf + (size_t)scol_[e] * 2048 + tid * 8);
      half8 hv = *(half8*)&qq;
      const float v = sval_[e];
#pragma unroll
      for (int k = 0; k < 8; ++k) acc[k] += v * (float)hv[k];
    }
    unsigned short o[8];
#pragma unroll
    for (int k = 0; k < 8; ++k) o[k] = f2h(acc[k]);
    *(uint4*)(Gh + (size_t)r * 2048 + tid * 8) = *(uint4*)o;
  }
}

// ---- 4. M = G*G^T/N + I — 128x128 tiles, BK=64, XOR-swizzled LDS (R34);
//      R35: reps loop (idempotent; rep-top barrier guards LDS reuse) ----
__device__ __forceinline__ void stageXY(const unsigned short* __restrict__ Gh,
                                        char* Xb, char* Yb,
                                        int row0, int col0, int k0,
                                        int w, int lane) {
  const int srcc = ((lane & 7) * 16) ^ ((lane >> 3) << 4);
#pragma unroll
  for (int q = 0; q < 2; ++q) {
    const int rl = w * 16 + q * 8 + (lane >> 3);          // local row
    __builtin_amdgcn_global_load_lds(
        AS1C((const char*)(Gh + (size_t)(row0 + rl) * 2048 + k0) + srcc),
        AS3(Xb + (w * 16 + q * 8) * 128), 16, 0, 0);
    __builtin_amdgcn_global_load_lds(
        AS1C((const char*)(Gh + (size_t)(col0 + rl) * 2048 + k0) + srcc),
        AS3(Yb + (w * 16 + q * 8) * 128), 16, 0, 0);
  }
}

__global__ __launch_bounds__(512) void gemmM_kernel(const unsigned short* __restrict__ Gh,
                                                    float* __restrict__ M,
                                                    int reps) {
  const int tid = threadIdx.x;
  // tile mapping: 16 diag (bi==bj) + 120 strict-lower (bi>bj, + mirror)
  int bi, bj;
  bool diag;
  if (blockIdx.x < 16) {
    bi = bj = blockIdx.x; diag = true;
  } else {
    int idx = blockIdx.x - 16;               // 0..119
    int j = 0;                                // off(j) = 15j - j(j-1)/2
    while (j < 15) {
      int offn = 15 * (j + 1) - (j + 1) * j / 2;
      if (idx < offn) break;
      ++j;
    }
    bj = j;
    int off = 15 * j - j * (j - 1) / 2;
    bi = j + 1 + (idx - off);
    diag = false;
  }

  __shared__ __align__(16) char smem[65536];
  float* LDSf = (float*)smem;

  const int w = tid >> 6, lane = tid & 63;
  const int row0 = bi * 128, col0 = bj * 128;
  const int mrow = lane & 15;
  const int crow = (lane >> 4) * 4, ccol = lane & 15;
  const int arow = w * 16 + mrow;            // A-frag local row
  const int xswA = (mrow & 7) << 4;          // read-side XOR (row&7)<<4

  for (int rep = 0; rep < reps; ++rep) {
    __syncthreads();                         // guard LDS reuse across reps
    f32x4 acc[8];
#pragma unroll
    for (int n = 0; n < 8; ++n) acc[n] = (f32x4){0.f, 0.f, 0.f, 0.f};

    stageXY(Gh, smem, smem + 32768, row0, col0, 0, w, lane);

    for (int t = 0; t < 32; ++t) {
      __syncthreads();                       // buf[t&1] resident; prev reads done
      if (t < 31)
        stageXY(Gh, smem + ((t + 1) & 1) * 16384, smem + 32768 + ((t + 1) & 1) * 16384,
                row0, col0, (t + 1) * 64, w, lane);
      const char* Xb = smem + (t & 1) * 16384;
      const char* Yb = smem + 32768 + (t & 1) * 16384;
#pragma unroll
      for (int kk = 0; kk < 2; ++kk) {
        const int cb = kk * 64 + (lane >> 4) * 16;   // byte col of 16B frag
        half8 af = *(const half8*)(Xb + arow * 128 + (cb ^ xswA));
#pragma unroll
        for (int nt = 0; nt < 8; ++nt) {
          const int nrow = nt * 16 + mrow;
          half8 bf = *(const half8*)(Yb + nrow * 128 + (cb ^ ((nrow & 7) << 4)));
          acc[nt] = __builtin_amdgcn_mfma_f32_16x16x32_f16(af, bf, acc[nt], 0, 0, 0);
        }
      }
    }
    // epilogue: direct write (always); mirror via LDS chunk (lower tiles)
    const float invn = 1.0f / 2048.0f;
    float vals[8][4];
#pragma unroll
    for (int nt = 0; nt < 8; ++nt) {
      const int gj = col0 + nt * 16 + ccol;
#pragma unroll
      for (int r = 0; r < 4; ++r) {
        const int gi = row0 + w * 16 + crow + r;
        float v = acc[nt][r] * invn + ((gi == gj) ? 1.0f : 0.0f);
        vals[nt][r] = v;
        M[(size_t)gi * 2048 + gj] = v;
      }
    }
    if (!diag) {
      __syncthreads();                       // staging reads done; LDSf safe
      for (int round = 0; round < 2; ++round) {
        if ((w >> 2) == round) {
          float* myc = LDSf + (w & 3) * (16 * 132);   // [16][132]
#pragma unroll
          for (int nt = 0; nt < 8; ++nt)
#pragma unroll
            for (int r = 0; r < 4; ++r)
              myc[(crow + r) * 132 + nt * 16 + ccol] = vals[nt][r];
          for (int u = 0; u < 32; ++u) {
            const int jj = u * 4 + (lane >> 4);       // tile col 0..127
            const int ii = lane & 15;                 // tile row-in-strip 0..15
            M[(size_t)(col0 + jj) * 2048 + row0 + w * 16 + ii] = myc[ii * 132 + jj];
          }
        }
        __syncthreads();
      }
    }
  }
}

// ---- deterministic block-wide sum over 8 waves: bitwise-identical per block ----
__device__ __forceinline__ float block_sum8(float v, float* red) {
#pragma unroll
  for (int off = 32; off; off >>= 1) v += __shfl_down(v, off);
  if ((threadIdx.x & 63) == 0) red[threadIdx.x >> 6] = v;
  __syncthreads();
  float r = ((red[0] + red[1]) + (red[2] + red[3])) +
            ((red[4] + red[5]) + (red[6] + red[7]));
  __syncthreads();
  return r;
}

// ---- 5. Lanczos: single-phase epoch protocol, 128 x 512 — FROZEN core (R20) ----
// R20: ~4.2 us/iter exchange is the store->remote-observability floor.
// RULE 1 (R1/R6): cross-block data via agent-scope atomics only.
// RULE 2 (R1/R6/R8): beta^2 = ||z - alpha v||^2 DIRECT form only.
// RULE 3 (R16): no fixed-address staging reuse with plain cached loads.
// RULE 4 (R17): exactly ONE publish->consume phase per iteration.
// RULE 5 (R19/R20): exchange cost is per-phase visibility latency.
// RULE 6 (R14/R15): no serial dependent-load chains anywhere.
// R32: sparse term S + S^T + SS^T traversed in-kernel (chain-free).
__global__ __launch_bounds__(512) void lanczos_kernel(const float* __restrict__ M,
                                                      const unsigned* __restrict__ cntR,
                                                      const int* __restrict__ binRc,
                                                      const float* __restrict__ binRv,
                                                      const unsigned* __restrict__ cntC,
                                                      const int* __restrict__ binCr,
                                                      const float* __restrict__ binCv,
                                                      unsigned long long* __restrict__ Z0,
                                                      unsigned long long* __restrict__ Z1,
                                                      float* __restrict__ out) {
  const int tid = threadIdx.x, b = blockIdx.x;
  const int wave = tid >> 6, lane = tid & 63;
  __shared__ __align__(16) float Mlds[16 * 2048];  // 128 KB: this block's 16 rows
  __shared__ __align__(16) float VA[2048];
  __shared__ __align__(16) float VB[2048];
  __shared__ float red[8];
  __shared__ float al[LK + 2], b2[LK + 2];
  __shared__ float bnds[2], res[2];

  const float* Mblk = M + (size_t)b * 16 * 2048;
#pragma unroll
  for (int q = 0; q < 16; ++q)
    __builtin_amdgcn_global_load_lds(AS1C(Mblk + wave * 4096 + q * 256 + lane * 4),
                                     AS3(Mlds + wave * 4096 + q * 256), 16, 0, 0);

  // block-redundant init: v1 = hash / ||hash||  (identical in every block), v0 = 0
  float pv[4];
  float part = 0.f;
#pragma unroll
  for (int t = 0; t < 4; ++t) {
    int i = t * 512 + tid;
    unsigned u = (unsigned)i * 2654435761u;
    u ^= u >> 16; u *= 2246822519u; u ^= u >> 13;
    float rv = (float)(u >> 8) * (2.f / 16777216.f) - 1.f;
    pv[t] = rv;
    part += rv * rv;
  }
  float nrm = block_sum8(part, red);       // barriers inside drain Mlds staging
  float innm = rsqrtf(nrm);
#pragma unroll
  for (int t = 0; t < 4; ++t) {
    int i = t * 512 + tid;
    VA[i] = pv[t] * innm;
    VB[i] = 0.f;
  }
  __syncthreads();                         // Mlds fully staged; VA/VB ready

  // ---- R32: in-kernel sparse traversal for this block's rows ----
  for (int rr = 0; rr < 2; ++rr) {
    const int r = b * 16 + wave * 2 + rr;
    float* Mrow = Mlds + (wave * 2 + rr) * 2048;
    const unsigned nR = min(cntR[r], (unsigned)BINCAP);
    const unsigned nC = min(cntC[r], (unsigned)BINCAP);
    // lane e holds row-bin entry e (parallel loads; one dependent hop to cntC)
    int c_ = 0; float v_ = 0.f; unsigned n_ = 0;
    if (lane < nR) {
      c_ = binRc[r * BINCAP + lane];
      v_ = binRv[r * BINCAP + lane];
      n_ = min(cntC[c_], (unsigned)BINCAP);
    }
    // S: M[r, c_e] += v_e
    if (lane < nR) atomicAdd(&Mrow[c_], v_);
    // S^T: column bin r -> M[r, j_e] += v_e
    if (lane < nC)
      atomicAdd(&Mrow[binCr[r * BINCAP + lane]], binCv[r * BINCAP + lane]);
    // SS^T: group g (16 lanes) expands entry e = g, g+4, ... via shfl-broadcast
    const unsigned g = lane >> 4, p0 = lane & 15;
    for (unsigned e = g; e < nR; e += 4) {
      const int c = __shfl(c_, (int)e);
      const float v = __shfl(v_, (int)e);
      const unsigned n2 = __shfl(n_, (int)e);
      for (unsigned p = p0; p < n2; p += 16)
        atomicAdd(&Mrow[binCr[c * BINCAP + p]], v * binCv[c * BINCAP + p]);
    }
  }
  __syncthreads();                         // sparse apply complete

  float* Vcur = VA;
  float* Vprev = VB;
  float beta_prev = 0.f;

  for (int j = 1; j <= LK; ++j) {
    unsigned long long* Z = (j & 1) ? Z0 : Z1;
#pragma unroll
    for (int rr = 0; rr < 2; ++rr) {
      const int r = b * 16 + wave * 2 + rr;
      const float4* Mr = (const float4*)(Mlds + (wave * 2 + rr) * 2048);
      float s = 0.f;
#pragma unroll
      for (int t = 0; t < 8; ++t) {
        int idx = t * 64 + lane;
        float4 m4 = Mr[idx];
        float4 v4 = ((const float4*)Vcur)[idx];
        s += m4.x * v4.x + m4.y * v4.y + m4.z * v4.z + m4.w * v4.w;
      }
#pragma unroll
      for (int off = 32; off; off >>= 1) s += __shfl_down(s, off);
      if (lane == 0) {
        float zv = s - beta_prev * Vprev[r];
        unsigned long long pk = ((unsigned long long)(unsigned)j << 32) |
                                (unsigned long long)(unsigned)__float_as_uint(zv);
        __hip_atomic_store(&Z[r], pk, __ATOMIC_RELAXED, AGENT);
      }
    }

    // hoist own v-slice reads (LDS) ahead of the poll — free overlap
    float va[4];
#pragma unroll
    for (int t = 0; t < 4; ++t) va[t] = Vcur[t * 512 + tid];

    unsigned long long w4[4];
    int rounds = 0;
    for (;;) {
      bool ok = true;
#pragma unroll
      for (int t = 0; t < 4; ++t) {
        w4[t] = __hip_atomic_load(&Z[t * 512 + tid], __ATOMIC_RELAXED, AGENT);
        ok &= ((unsigned)(w4[t] >> 32) == (unsigned)j);
      }
      if (ok) break;
      if (rounds == 1)      __builtin_amdgcn_s_sleep(1);   //  64 clk
      else if (rounds == 2) __builtin_amdgcn_s_sleep(2);   // 128 clk
      else if (rounds >= 3) __builtin_amdgcn_s_sleep(8);   // 512 clk
      ++rounds;
    }
    float za[4];
    float pa = 0.f;
#pragma unroll
    for (int t = 0; t < 4; ++t) {
      za[t] = __uint_as_float((unsigned)w4[t]);
      pa += za[t] * va[t];
    }
    float alpha = block_sum8(pa, red);
    float pb = 0.f;
#pragma unroll
    for (int t = 0; t < 4; ++t) {
      float rsd = za[t] - alpha * va[t];
      pb += rsd * rsd;
    }
    float beta2 = block_sum8(pb, red);
    float beta = sqrtf(fmaxf(beta2, 1e-30f));
    float invb = 1.f / beta;
    if (tid == 0) { al[j] = alpha; b2[j] = beta2; }
#pragma unroll
    for (int t = 0; t < 4; ++t) {
      int i = t * 512 + tid;
      Vprev[i] = (za[t] - alpha * va[t]) * invb;
    }
    float* tmp = Vprev; Vprev = Vcur; Vcur = tmp;
    beta_prev = beta;
    __syncthreads();
  }

  // ---- extreme eigenvalues of T via Sturm bisection (block 0) ----
  if (b == 0) {
    if (tid == 0) {                                  // Gershgorin bounds on T
      float lo = 1e30f, hi = -1e30f;
      for (int i = 1; i <= LK; ++i) {
        float bl = (i > 1) ? sqrtf(b2[i - 1]) : 0.f;
        float br = (i < LK) ? sqrtf(b2[i]) : 0.f;
        lo = fminf(lo, al[i] - bl - br);
        hi = fmaxf(hi, al[i] + bl + br);
      }
      bnds[0] = lo; bnds[1] = hi;
    }
    __syncthreads();
    if (wave < 2) {                 // wave 0 -> lambda_min, wave 1 -> lambda_max
      const int tcount = (wave == 0) ? 1 : LK;
      float lo = bnds[0], hi = bnds[1];
      for (int round = 0; round < 4; ++round) {
        float x = lo + (hi - lo) * (float)(lane + 1) * (1.f / 65.f);
        int cnt = 0;                                 // #eigs of T below x
        float d = al[1] - x;
        if (fabsf(d) < 1e-25f) d = -1e-25f;
        if (d < 0.f) cnt++;
        for (int i = 2; i <= LK; ++i) {
          d = (al[i] - x) - b2[i - 1] / d;
          if (fabsf(d) < 1e-25f) d = -1e-25f;
          if (d < 0.f) cnt++;
        }
        bool ab = (cnt >= tcount);                   // x is above the target eig
        float cand_hi = ab ? x : hi;
        float cand_lo = ab ? lo : x;
#pragma unroll
        for (int off = 32; off; off >>= 1) {
          cand_hi = fminf(cand_hi, __shfl_down(cand_hi, off));
          cand_lo = fmaxf(cand_lo, __shfl_down(cand_lo, off));
        }
        cand_hi = __shfl(cand_hi, 0);
        cand_lo = __shfl(cand_lo, 0);
        hi = cand_hi;
        lo = fminf(cand_lo, hi);
      }
      if (lane == 0) res[wave] = 0.5f * (lo + hi);
    }
    __syncthreads();
    if (tid == 0) {
      float lmin = fmaxf(res[0], 1e-12f);
      float lmax = fmaxf(res[1], 1e-12f);
      out[0] = logf(lmax) - logf(lmin);
    }
  }
}

extern "C" void kernel_launch(void* const* d_in, const int* in_sizes, int n_in,
                              void* d_out, int out_size, void* d_ws, size_t ws_size,
                              hipStream_t stream) {
  const float* pred = (const float*)d_in[0];
  const float* scal = (const float*)d_in[1];
  const float* W    = (const float*)d_in[2];
  const int*   rows = (const int*)d_in[3];
  const int*   cols = (const int*)d_in[4];
  float* out = (float*)d_out;

  // workspace layout (peak ~34.2 MB):
  //  [0,8MB)   : Hf fp16
  //  [8,16MB)  : Gh fp16 (G = L*Wh)
  //  [16,32MB) : M fp32
  //  [32MB,..) : cntR 8KB | cntC 8KB | binRc 512KB | binRv 512KB |
  //              binCr 512KB | binCv 512KB | Z0 16KB | Z1 16KB
  char* ws = (char*)d_ws;
  const size_t MB = 1024 * 1024;
  unsigned short* Hf = (unsigned short*)(ws);
  unsigned short* Gh = (unsigned short*)(ws + 8 * MB);
  float* M = (float*)(ws + 16 * MB);
  char* ctrl = ws + 32 * MB;
  unsigned* cntR = (unsigned*)(ctrl);
  unsigned* cntC = (unsigned*)(ctrl + 8192);
  int*      binRc = (int*)(ctrl + 16384);
  float*    binRv = (float*)(ctrl + 16384 + 524288);
  int*      binCr = (int*)(ctrl + 16384 + 2 * 524288);
  float*    binCv = (float*)(ctrl + 16384 + 3 * 524288);
  unsigned long long* Z0 = (unsigned long long*)(ctrl + 16384 + 4 * 524288);
  unsigned long long* Z1 = (unsigned long long*)(ctrl + 16384 + 4 * 524288 + 16384);

  convert_kernel<<<4096, 256, 0, stream>>>(W, Hf, cntR, cntC);
  fill_kernel<<<NNZ / 256, 256, 0, stream>>>(pred, scal, rows, cols,
                                             cntR, binRc, binRv, cntC, binCr, binCv);
  // MEASUREMENT: reps=8 — single-shot cost = dispatch_dur / 8
  gatherG_kernel<<<2048, 256, 0, stream>>>(cntR, binRc, binRv, Hf, Gh, 8);
  gemmM_kernel<<<136, 512, 0, stream>>>(Gh, M, 8);
  lanczos_kernel<<<NBL, 512, 0, stream>>>(M, cntR, binRc, binRv,
                                          cntC, binCr, binCv, Z0, Z1, out);
}

// Round 21
// 382.162 us; speedup vs baseline: 1.1746x; 1.1746x over previous
//
#include <hip/hip_runtime.h>
#include <hip/hip_cooperative_groups.h>

namespace cg = cooperative_groups;

// Problem constants (fixed by the reference)
#define N2 2048
#define NNZ 32768
#define LK 22          // FROZEN: absmax 0.0234 of 0.037 threshold
#define BINCAP 64      // slots per bin (Poisson(16) tail ~1e-15)

typedef __attribute__((ext_vector_type(8))) _Float16 half8;
typedef __attribute__((ext_vector_type(4))) float f32x4;

#define AGENT __HIP_MEMORY_SCOPE_AGENT
#define AS1C(p) ((const __attribute__((address_space(1))) unsigned int*)(p))
#define AS3(p)  ((__attribute__((address_space(3))) unsigned int*)(p))

__device__ __forceinline__ unsigned short f2h(float f) {
  _Float16 h = (_Float16)f;                   // fp16 RNE
  return *(unsigned short*)&h;
}

// ==== R36: ONE cooperative mega-kernel.
// R20 measurement: kernels sum to ~161us but wall = 245us — ~84us lives in
// the 4 inter-dispatch boundaries (~17us each), which is why five gemmM
// levers were null. Phases fused with cg::grid.sync() (vetted fence path
// for cross-XCD visibility; Rule 1 applies to UNfenced exchange only — the
// lanczos Z-protocol stays agent-scope-atomic as before).
//   P0 convert (W->Hf fp16; zero bins)      all 256 blocks
//   P1 fill row/col bins                    all
//   P2 gatherG: G = (I+S) Wh                all (8 rows/block, 2x256 thr)
//   P3 gemmM: M = G G^T/N + I               blocks 0..135 (R34 body, verbatim)
//   P4 lanczos + sparse apply + Sturm       blocks 0..127 (frozen body)
// Blocks >=128 return after the last grid.sync (no sync after exit).

__device__ __forceinline__ void stageXY(const unsigned short* __restrict__ Gh,
                                        char* Xb, char* Yb,
                                        int row0, int col0, int k0,
                                        int w, int lane) {
  const int srcc = ((lane & 7) * 16) ^ ((lane >> 3) << 4);
#pragma unroll
  for (int q = 0; q < 2; ++q) {
    const int rl = w * 16 + q * 8 + (lane >> 3);          // local row
    __builtin_amdgcn_global_load_lds(
        AS1C((const char*)(Gh + (size_t)(row0 + rl) * 2048 + k0) + srcc),
        AS3(Xb + (w * 16 + q * 8) * 128), 16, 0, 0);
    __builtin_amdgcn_global_load_lds(
        AS1C((const char*)(Gh + (size_t)(col0 + rl) * 2048 + k0) + srcc),
        AS3(Yb + (w * 16 + q * 8) * 128), 16, 0, 0);
  }
}

__device__ __forceinline__ float block_sum8(float v, float* red) {
#pragma unroll
  for (int off = 32; off; off >>= 1) v += __shfl_down(v, off);
  if ((threadIdx.x & 63) == 0) red[threadIdx.x >> 6] = v;
  __syncthreads();
  float r = ((red[0] + red[1]) + (red[2] + red[3])) +
            ((red[4] + red[5]) + (red[6] + red[7]));
  __syncthreads();
  return r;
}

__global__ __launch_bounds__(512) void mega_kernel(
    const float* __restrict__ W, const float* __restrict__ pred,
    const float* __restrict__ scal, const int* __restrict__ rows,
    const int* __restrict__ cols,
    unsigned short* __restrict__ Hf, unsigned short* __restrict__ Gh,
    float* __restrict__ M,
    unsigned* __restrict__ cntR, int* __restrict__ binRc, float* __restrict__ binRv,
    unsigned* __restrict__ cntC, int* __restrict__ binCr, float* __restrict__ binCv,
    unsigned long long* __restrict__ Z0, unsigned long long* __restrict__ Z1,
    float* __restrict__ out) {
  cg::grid_group grid = cg::this_grid();
  const int tid = threadIdx.x, b = blockIdx.x;
  const int gid = b * 512 + tid;             // 0..131071
  const int wave = tid >> 6, lane = tid & 63;

  // LDS (lanczos-phase layout, 147.9KB -> 1 block/CU, 256 co-resident):
  __shared__ __align__(16) float Mlds[16 * 2048];   // gemmM aliases this (64KB)
  __shared__ __align__(16) float VA[2048];          // gatherG bins alias this
  __shared__ __align__(16) float VB[2048];
  __shared__ float red[8];
  __shared__ float al[LK + 2], b2v[LK + 2];
  __shared__ float bnds[2], res[2];

  // ---- P0: zero bins + convert W -> Hf (fp16) ----
  if (gid < 2048)            cntR[gid] = 0;
  else if (gid < 4096)       cntC[gid - 2048] = 0;
  for (int i4 = gid; i4 < 1048576; i4 += 131072) {
    float4 w4 = ((const float4*)W)[i4];
    ushort4 h;
    h.x = f2h(w4.x); h.y = f2h(w4.y); h.z = f2h(w4.z); h.w = f2h(w4.w);
    ((ushort4*)Hf)[i4] = h;
  }
  grid.sync();

  // ---- P1: fill row/col bins ----
  if (gid < NNZ) {
    int r = rows[gid], c = cols[gid];
    float v = pred[gid] * scal[gid];
    unsigned pR = atomicAdd(&cntR[r], 1u);
    if (pR < BINCAP) { binRc[r * BINCAP + pR] = c; binRv[r * BINCAP + pR] = v; }
    unsigned pC = atomicAdd(&cntC[c], 1u);
    if (pC < BINCAP) { binCr[c * BINCAP + pC] = r; binCv[c * BINCAP + pC] = v; }
  }
  grid.sync();

  // ---- P2: gatherG — G[r,:] = Hf[r,:] + sum v_e Hf[c_e,:]  (8 rows/block) ----
  {
    int* sc_ = (int*)VA;                     // 2 x BINCAP ints
    float* sv_ = (float*)VB;
    for (int it = 0; it < 4; ++it) {
      const int sub = tid >> 8;              // 0..1 (row group)
      const int t2 = tid & 255;
      const int r = b * 8 + it * 2 + sub;
      int* sc = sc_ + sub * BINCAP;
      float* sv = sv_ + sub * BINCAP;
      const unsigned ne = min(cntR[r], (unsigned)BINCAP);
      if (t2 < (int)ne) {
        sc[t2] = binRc[r * BINCAP + t2];
        sv[t2] = binRv[r * BINCAP + t2];
      }
      __syncthreads();
      uint4 own = *(const uint4*)(Hf + (size_t)r * 2048 + t2 * 8);
      half8 ho = *(half8*)&own;
      float acc[8];
#pragma unroll
      for (int k = 0; k < 8; ++k) acc[k] = (float)ho[k];
      unsigned e = 0;
      for (; e + 8 <= ne; e += 8) {
        uint4 q[8];
#pragma unroll
        for (int u = 0; u < 8; ++u)
          q[u] = *(const uint4*)(Hf + (size_t)sc[e + u] * 2048 + t2 * 8);
#pragma unroll
        for (int u = 0; u < 8; ++u) {
          half8 hv = *(half8*)&q[u];
          const float v = sv[e + u];
#pragma unroll
          for (int k = 0; k < 8; ++k) acc[k] += v * (float)hv[k];
        }
      }
      for (; e + 4 <= ne; e += 4) {
        uint4 q[4];
#pragma unroll
        for (int u = 0; u < 4; ++u)
          q[u] = *(const uint4*)(Hf + (size_t)sc[e + u] * 2048 + t2 * 8);
#pragma unroll
        for (int u = 0; u < 4; ++u) {
          half8 hv = *(half8*)&q[u];
          const float v = sv[e + u];
#pragma unroll
          for (int k = 0; k < 8; ++k) acc[k] += v * (float)hv[k];
        }
      }
      for (; e < ne; ++e) {
        uint4 qq = *(const uint4*)(Hf + (size_t)sc[e] * 2048 + t2 * 8);
        half8 hv = *(half8*)&qq;
        const float v = sv[e];
#pragma unroll
        for (int k = 0; k < 8; ++k) acc[k] += v * (float)hv[k];
      }
      unsigned short o[8];
#pragma unroll
      for (int k = 0; k < 8; ++k) o[k] = f2h(acc[k]);
      *(uint4*)(Gh + (size_t)r * 2048 + t2 * 8) = *(uint4*)o;
      __syncthreads();                       // before next it reuses sc/sv
    }
  }
  grid.sync();

  // ---- P3: gemmM — M = G G^T/N + I  (blocks 0..135; R34 body, LDS=Mlds) ----
  if (b < 136) {
    char* smem = (char*)Mlds;                // 64KB staging aliases Mlds
    float* LDSf = (float*)smem;
    int bi, bj;
    bool diag;
    if (b < 16) {
      bi = bj = b; diag = true;
    } else {
      int idx = b - 16;                      // 0..119
      int j = 0;
      while (j < 15) {
        int offn = 15 * (j + 1) - (j + 1) * j / 2;
        if (idx < offn) break;
        ++j;
      }
      bj = j;
      int off = 15 * j - j * (j - 1) / 2;
      bi = j + 1 + (idx - off);
      diag = false;
    }
    const int w = wave;
    const int row0 = bi * 128, col0 = bj * 128;
    const int mrow = lane & 15;
    const int crow = (lane >> 4) * 4, ccol = lane & 15;
    const int arow = w * 16 + mrow;
    const int xswA = (mrow & 7) << 4;
    f32x4 acc[8];
#pragma unroll
    for (int n = 0; n < 8; ++n) acc[n] = (f32x4){0.f, 0.f, 0.f, 0.f};

    stageXY(Gh, smem, smem + 32768, row0, col0, 0, w, lane);
    for (int t = 0; t < 32; ++t) {
      __syncthreads();
      if (t < 31)
        stageXY(Gh, smem + ((t + 1) & 1) * 16384,
                smem + 32768 + ((t + 1) & 1) * 16384,
                row0, col0, (t + 1) * 64, w, lane);
      const char* Xb = smem + (t & 1) * 16384;
      const char* Yb = smem + 32768 + (t & 1) * 16384;
#pragma unroll
      for (int kk = 0; kk < 2; ++kk) {
        const int cb = kk * 64 + (lane >> 4) * 16;
        half8 af = *(const half8*)(Xb + arow * 128 + (cb ^ xswA));
#pragma unroll
        for (int nt = 0; nt < 8; ++nt) {
          const int nrow = nt * 16 + mrow;
          half8 bf = *(const half8*)(Yb + nrow * 128 + (cb ^ ((nrow & 7) << 4)));
          acc[nt] = __builtin_amdgcn_mfma_f32_16x16x32_f16(af, bf, acc[nt], 0, 0, 0);
        }
      }
    }
    const float invn = 1.0f / 2048.0f;
    float vals[8][4];
#pragma unroll
    for (int nt = 0; nt < 8; ++nt) {
      const int gj = col0 + nt * 16 + ccol;
#pragma unroll
      for (int r = 0; r < 4; ++r) {
        const int gi = row0 + w * 16 + crow + r;
        float v = acc[nt][r] * invn + ((gi == gj) ? 1.0f : 0.0f);
        vals[nt][r] = v;
        M[(size_t)gi * 2048 + gj] = v;
      }
    }
    if (!diag) {
      __syncthreads();
      for (int round = 0; round < 2; ++round) {
        if ((w >> 2) == round) {
          float* myc = LDSf + (w & 3) * (16 * 132);
#pragma unroll
          for (int nt = 0; nt < 8; ++nt)
#pragma unroll
            for (int r = 0; r < 4; ++r)
              myc[(crow + r) * 132 + nt * 16 + ccol] = vals[nt][r];
          for (int u = 0; u < 32; ++u) {
            const int jj = u * 4 + (lane >> 4);
            const int ii = lane & 15;
            M[(size_t)(col0 + jj) * 2048 + row0 + w * 16 + ii] = myc[ii * 132 + jj];
          }
        }
        __syncthreads();
      }
    }
  }
  grid.sync();                               // last grid-wide sync

  // ---- P4: lanczos (blocks 0..127) — FROZEN core (R20 rules 1-6, R32) ----
  if (b >= 128) return;

  const float* Mblk = M + (size_t)b * 16 * 2048;
#pragma unroll
  for (int q = 0; q < 16; ++q)
    __builtin_amdgcn_global_load_lds(AS1C(Mblk + wave * 4096 + q * 256 + lane * 4),
                                     AS3(Mlds + wave * 4096 + q * 256), 16, 0, 0);

  float pv[4];
  float part = 0.f;
#pragma unroll
  for (int t = 0; t < 4; ++t) {
    int i = t * 512 + tid;
    unsigned u = (unsigned)i * 2654435761u;
    u ^= u >> 16; u *= 2246822519u; u ^= u >> 13;
    float rv = (float)(u >> 8) * (2.f / 16777216.f) - 1.f;
    pv[t] = rv;
    part += rv * rv;
  }
  float nrm = block_sum8(part, red);         // barriers drain Mlds staging
  float innm = rsqrtf(nrm);
#pragma unroll
  for (int t = 0; t < 4; ++t) {
    int i = t * 512 + tid;
    VA[i] = pv[t] * innm;
    VB[i] = 0.f;
  }
  __syncthreads();

  // in-kernel sparse traversal (R32, chain-free)
  for (int rr = 0; rr < 2; ++rr) {
    const int r = b * 16 + wave * 2 + rr;
    float* Mrow = Mlds + (wave * 2 + rr) * 2048;
    const unsigned nR = min(cntR[r], (unsigned)BINCAP);
    const unsigned nC = min(cntC[r], (unsigned)BINCAP);
    int c_ = 0; float v_ = 0.f; unsigned n_ = 0;
    if (lane < (int)nR) {
      c_ = binRc[r * BINCAP + lane];
      v_ = binRv[r * BINCAP + lane];
      n_ = min(cntC[c_], (unsigned)BINCAP);
    }
    if (lane < (int)nR) atomicAdd(&Mrow[c_], v_);
    if (lane < (int)nC)
      atomicAdd(&Mrow[binCr[r * BINCAP + lane]], binCv[r * BINCAP + lane]);
    const unsigned g = lane >> 4, p0 = lane & 15;
    for (unsigned e = g; e < nR; e += 4) {
      const int c = __shfl(c_, (int)e);
      const float v = __shfl(v_, (int)e);
      const unsigned n2 = __shfl(n_, (int)e);
      for (unsigned p = p0; p < n2; p += 16)
        atomicAdd(&Mrow[binCr[c * BINCAP + p]], v * binCv[c * BINCAP + p]);
    }
  }
  __syncthreads();

  float* Vcur = VA;
  float* Vprev = VB;
  float beta_prev = 0.f;

  for (int j = 1; j <= LK; ++j) {
    unsigned long long* Z = (j & 1) ? Z0 : Z1;
#pragma unroll
    for (int rr = 0; rr < 2; ++rr) {
      const int r = b * 16 + wave * 2 + rr;
      const float4* Mr = (const float4*)(Mlds + (wave * 2 + rr) * 2048);
      float s = 0.f;
#pragma unroll
      for (int t = 0; t < 8; ++t) {
        int idx = t * 64 + lane;
        float4 m4 = Mr[idx];
        float4 v4 = ((const float4*)Vcur)[idx];
        s += m4.x * v4.x + m4.y * v4.y + m4.z * v4.z + m4.w * v4.w;
      }
#pragma unroll
      for (int off = 32; off; off >>= 1) s += __shfl_down(s, off);
      if (lane == 0) {
        float zv = s - beta_prev * Vprev[r];
        unsigned long long pk = ((unsigned long long)(unsigned)j << 32) |
                                (unsigned long long)(unsigned)__float_as_uint(zv);
        __hip_atomic_store(&Z[r], pk, __ATOMIC_RELAXED, AGENT);
      }
    }

    float va[4];
#pragma unroll
    for (int t = 0; t < 4; ++t) va[t] = Vcur[t * 512 + tid];

    unsigned long long w4[4];
    int rounds = 0;
    for (;;) {
      bool ok = true;
#pragma unroll
      for (int t = 0; t < 4; ++t) {
        w4[t] = __hip_atomic_load(&Z[t * 512 + tid], __ATOMIC_RELAXED, AGENT);
        ok &= ((unsigned)(w4[t] >> 32) == (unsigned)j);
      }
      if (ok) break;
      if (rounds == 1)      __builtin_amdgcn_s_sleep(1);
      else if (rounds == 2) __builtin_amdgcn_s_sleep(2);
      else if (rounds >= 3) __builtin_amdgcn_s_sleep(8);
      ++rounds;
    }
    float za[4];
    float pa = 0.f;
#pragma unroll
    for (int t = 0; t < 4; ++t) {
      za[t] = __uint_as_float((unsigned)w4[t]);
      pa += za[t] * va[t];
    }
    float alpha = block_sum8(pa, red);
    float pb = 0.f;
#pragma unroll
    for (int t = 0; t < 4; ++t) {
      float rsd = za[t] - alpha * va[t];
      pb += rsd * rsd;
    }
    float beta2 = block_sum8(pb, red);
    float beta = sqrtf(fmaxf(beta2, 1e-30f));
    float invb = 1.f / beta;
    if (tid == 0) { al[j] = alpha; b2v[j] = beta2; }
#pragma unroll
    for (int t = 0; t < 4; ++t) {
      int i = t * 512 + tid;
      Vprev[i] = (za[t] - alpha * va[t]) * invb;
    }
    float* tmp = Vprev; Vprev = Vcur; Vcur = tmp;
    beta_prev = beta;
    __syncthreads();
  }

  // ---- Sturm bisection (block 0) ----
  if (b == 0) {
    if (tid == 0) {
      float lo = 1e30f, hi = -1e30f;
      for (int i = 1; i <= LK; ++i) {
        float bl = (i > 1) ? sqrtf(b2v[i - 1]) : 0.f;
        float br = (i < LK) ? sqrtf(b2v[i]) : 0.f;
        lo = fminf(lo, al[i] - bl - br);
        hi = fmaxf(hi, al[i] + bl + br);
      }
      bnds[0] = lo; bnds[1] = hi;
    }
    __syncthreads();
    if (wave < 2) {
      const int tcount = (wave == 0) ? 1 : LK;
      float lo = bnds[0], hi = bnds[1];
      for (int round = 0; round < 4; ++round) {
        float x = lo + (hi - lo) * (float)(lane + 1) * (1.f / 65.f);
        int cnt = 0;
        float d = al[1] - x;
        if (fabsf(d) < 1e-25f) d = -1e-25f;
        if (d < 0.f) cnt++;
        for (int i = 2; i <= LK; ++i) {
          d = (al[i] - x) - b2v[i - 1] / d;
          if (fabsf(d) < 1e-25f) d = -1e-25f;
          if (d < 0.f) cnt++;
        }
        bool ab = (cnt >= tcount);
        float cand_hi = ab ? x : hi;
        float cand_lo = ab ? lo : x;
#pragma unroll
        for (int off = 32; off; off >>= 1) {
          cand_hi = fminf(cand_hi, __shfl_down(cand_hi, off));
          cand_lo = fmaxf(cand_lo, __shfl_down(cand_lo, off));
        }
        cand_hi = __shfl(cand_hi, 0);
        cand_lo = __shfl(cand_lo, 0);
        hi = cand_hi;
        lo = fminf(cand_lo, hi);
      }
      if (lane == 0) res[wave] = 0.5f * (lo + hi);
    }
    __syncthreads();
    if (tid == 0) {
      float lmin = fmaxf(res[0], 1e-12f);
      float lmax = fmaxf(res[1], 1e-12f);
      out[0] = logf(lmax) - logf(lmin);
    }
  }
}

extern "C" void kernel_launch(void* const* d_in, const int* in_sizes, int n_in,
                              void* d_out, int out_size, void* d_ws, size_t ws_size,
                              hipStream_t stream) {
  const float* pred = (const float*)d_in[0];
  const float* scal = (const float*)d_in[1];
  const float* W    = (const float*)d_in[2];
  const int*   rows = (const int*)d_in[3];
  const int*   cols = (const int*)d_in[4];
  float* out = (float*)d_out;

  // workspace layout (peak ~34.2 MB):
  //  [0,8MB)   : Hf fp16
  //  [8,16MB)  : Gh fp16 (G = L*Wh)
  //  [16,32MB) : M fp32
  //  [32MB,..) : cntR 8KB | cntC 8KB | binRc 512KB | binRv 512KB |
  //              binCr 512KB | binCv 512KB | Z0 16KB | Z1 16KB
  char* ws = (char*)d_ws;
  const size_t MB = 1024 * 1024;
  unsigned short* Hf = (unsigned short*)(ws);
  unsigned short* Gh = (unsigned short*)(ws + 8 * MB);
  float* M = (float*)(ws + 16 * MB);
  char* ctrl = ws + 32 * MB;
  unsigned* cntR = (unsigned*)(ctrl);
  unsigned* cntC = (unsigned*)(ctrl + 8192);
  int*      binRc = (int*)(ctrl + 16384);
  float*    binRv = (float*)(ctrl + 16384 + 524288);
  int*      binCr = (int*)(ctrl + 16384 + 2 * 524288);
  float*    binCv = (float*)(ctrl + 16384 + 3 * 524288);
  unsigned long long* Z0 = (unsigned long long*)(ctrl + 16384 + 4 * 524288);
  unsigned long long* Z1 = (unsigned long long*)(ctrl + 16384 + 4 * 524288 + 16384);

  void* kargs[] = {
    (void*)&W, (void*)&pred, (void*)&scal, (void*)&rows, (void*)&cols,
    (void*)&Hf, (void*)&Gh, (void*)&M,
    (void*)&cntR, (void*)&binRc, (void*)&binRv,
    (void*)&cntC, (void*)&binCr, (void*)&binCv,
    (void*)&Z0, (void*)&Z1, (void*)&out
  };
  hipLaunchCooperativeKernel((const void*)mega_kernel, dim3(256), dim3(512),
                             kargs, 0, stream);
}

// Round 22
// 245.470 us; speedup vs baseline: 1.8286x; 1.5569x over previous
//
#include <hip/hip_runtime.h>

// Problem constants (fixed by the reference)
#define N2 2048
#define NNZ 32768
#define LK 22          // FROZEN: absmax 0.0234 of 0.037 threshold (3 of ~4.7 bf16 ulps)
#define NBL 128        // lanczos grid blocks: 128 x 512 thr; 147KB LDS -> 1 block/CU
#define BINCAP 64      // slots per bin (Poisson(16) tail ~1e-15)

typedef __attribute__((ext_vector_type(8))) _Float16 half8;
typedef __attribute__((ext_vector_type(4))) float f32x4;

#define AGENT __HIP_MEMORY_SCOPE_AGENT
#define AS1C(p) ((const __attribute__((address_space(1))) unsigned int*)(p))
#define AS3(p)  ((__attribute__((address_space(3))) unsigned int*)(p))

__device__ __forceinline__ unsigned short f2h(float f) {
  _Float16 h = (_Float16)f;                   // fp16 RNE
  return *(unsigned short*)&h;
}

// ==== R37 = R19 revert (best verified: 245.4us).
// Final ledger (R20 reps-measurement + R21 fusion experiment):
//   kernels ~161us  = lanczos 125.5 (frozen: ~4.2us/iter agent-scope
//                     visibility floor, invariant to protocol shape/traffic/
//                     agent count, R0-R4) + gemmM 23 (5 levers null; HBM/L2
//                     panel-bound at this size) + convert/fill/gatherG ~13
//   + ~84us FIXED harness overhead (R21: single-kernel fusion left the gap
//     unchanged at ~81us while grid.sync cache-flushes added +140 kernel
//     time -> fusion rejected).
// This is the practical plateau for this harness.

// ---- 1. W (fp32) -> fp16; zero row/col bin counters ----
__global__ __launch_bounds__(256) void convert_kernel(const float* __restrict__ W,
                                                      unsigned short* __restrict__ Hf,
                                                      unsigned* __restrict__ cntR,
                                                      unsigned* __restrict__ cntC) {
  if (blockIdx.x < 8)       cntR[blockIdx.x * 256 + threadIdx.x] = 0;
  else if (blockIdx.x < 16) cntC[(blockIdx.x - 8) * 256 + threadIdx.x] = 0;
  int i4 = blockIdx.x * 256 + threadIdx.x;          // grid 4096 -> 1048576 float4s
  float4 w = ((const float4*)W)[i4];
  ushort4 h;
  h.x = f2h(w.x); h.y = f2h(w.y); h.z = f2h(w.z); h.w = f2h(w.w);
  ((ushort4*)Hf)[i4] = h;
}

// ---- 2. fill row bins (G-gather, SS^T) and column bins (S^T, SS^T) ----
__global__ __launch_bounds__(256) void fill_kernel(const float* __restrict__ pred,
                                                   const float* __restrict__ scal,
                                                   const int* __restrict__ rows,
                                                   const int* __restrict__ cols,
                                                   unsigned* __restrict__ cntR,
                                                   int* __restrict__ binRc,
                                                   float* __restrict__ binRv,
                                                   unsigned* __restrict__ cntC,
                                                   int* __restrict__ binCr,
                                                   float* __restrict__ binCv) {
  int k = blockIdx.x * 256 + threadIdx.x;
  int r = rows[k], c = cols[k];
  float v = pred[k] * scal[k];
  unsigned pR = atomicAdd(&cntR[r], 1u);
  if (pR < BINCAP) { binRc[r * BINCAP + pR] = c; binRv[r * BINCAP + pR] = v; }
  unsigned pC = atomicAdd(&cntC[c], 1u);
  if (pC < BINCAP) { binCr[c * BINCAP + pC] = r; binCv[c * BINCAP + pC] = v; }
}

// ---- 3. G[r,:] = Hf[r,:] + sum_e v_e * Hf[c_e,:]  (fp16 out, fp32 acc, MLP-8) ----
__global__ __launch_bounds__(256) void gatherG_kernel(const unsigned* __restrict__ cntR,
                                                      const int* __restrict__ binRc,
                                                      const float* __restrict__ binRv,
                                                      const unsigned short* __restrict__ Hf,
                                                      unsigned short* __restrict__ Gh) {
  const int r = blockIdx.x, tid = threadIdx.x;
  __shared__ int scol_[BINCAP];
  __shared__ float sval_[BINCAP];
  const unsigned ne = min(cntR[r], (unsigned)BINCAP);
  if (tid < ne) {
    scol_[tid] = binRc[r * BINCAP + tid];
    sval_[tid] = binRv[r * BINCAP + tid];
  }
  __syncthreads();
  // init from own row (the I in L = I + S)
  uint4 own = *(const uint4*)(Hf + (size_t)r * 2048 + tid * 8);
  half8 ho = *(half8*)&own;
  float acc[8];
#pragma unroll
  for (int k = 0; k < 8; ++k) acc[k] = (float)ho[k];
  unsigned e = 0;
  for (; e + 8 <= ne; e += 8) {
    uint4 q[8];
#pragma unroll
    for (int u = 0; u < 8; ++u)
      q[u] = *(const uint4*)(Hf + (size_t)scol_[e + u] * 2048 + tid * 8);
#pragma unroll
    for (int u = 0; u < 8; ++u) {
      half8 hv = *(half8*)&q[u];
      const float v = sval_[e + u];
#pragma unroll
      for (int k = 0; k < 8; ++k) acc[k] += v * (float)hv[k];
    }
  }
  for (; e + 4 <= ne; e += 4) {
    uint4 q[4];
#pragma unroll
    for (int u = 0; u < 4; ++u)
      q[u] = *(const uint4*)(Hf + (size_t)scol_[e + u] * 2048 + tid * 8);
#pragma unroll
    for (int u = 0; u < 4; ++u) {
      half8 hv = *(half8*)&q[u];
      const float v = sval_[e + u];
#pragma unroll
      for (int k = 0; k < 8; ++k) acc[k] += v * (float)hv[k];
    }
  }
  for (; e < ne; ++e) {
    uint4 qq = *(const uint4*)(Hf + (size_t)scol_[e] * 2048 + tid * 8);
    half8 hv = *(half8*)&qq;
    const float v = sval_[e];
#pragma unroll
    for (int k = 0; k < 8; ++k) acc[k] += v * (float)hv[k];
  }
  unsigned short o[8];
#pragma unroll
  for (int k = 0; k < 8; ++k) o[k] = f2h(acc[k]);
  *(uint4*)(Gh + (size_t)r * 2048 + tid * 8) = *(uint4*)o;
}

// ---- 4. M = G*G^T/N + I — 128x128 tiles, BK=64, XOR-swizzled LDS (R34) ----
__device__ __forceinline__ void stageXY(const unsigned short* __restrict__ Gh,
                                        char* Xb, char* Yb,
                                        int row0, int col0, int k0,
                                        int w, int lane) {
  const int srcc = ((lane & 7) * 16) ^ ((lane >> 3) << 4);
#pragma unroll
  for (int q = 0; q < 2; ++q) {
    const int rl = w * 16 + q * 8 + (lane >> 3);          // local row
    __builtin_amdgcn_global_load_lds(
        AS1C((const char*)(Gh + (size_t)(row0 + rl) * 2048 + k0) + srcc),
        AS3(Xb + (w * 16 + q * 8) * 128), 16, 0, 0);
    __builtin_amdgcn_global_load_lds(
        AS1C((const char*)(Gh + (size_t)(col0 + rl) * 2048 + k0) + srcc),
        AS3(Yb + (w * 16 + q * 8) * 128), 16, 0, 0);
  }
}

__global__ __launch_bounds__(512) void gemmM_kernel(const unsigned short* __restrict__ Gh,
                                                    float* __restrict__ M) {
  const int tid = threadIdx.x;
  // tile mapping: 16 diag (bi==bj, symmetric tile, full write) +
  //               120 strict-lower (bi>bj, direct + mirrored write)
  int bi, bj;
  bool diag;
  if (blockIdx.x < 16) {
    bi = bj = blockIdx.x; diag = true;
  } else {
    int idx = blockIdx.x - 16;               // 0..119
    int j = 0;                                // off(j) = 15j - j(j-1)/2
    while (j < 15) {
      int offn = 15 * (j + 1) - (j + 1) * j / 2;
      if (idx < offn) break;
      ++j;
    }
    bj = j;
    int off = 15 * j - j * (j - 1) / 2;
    bi = j + 1 + (idx - off);
    diag = false;
  }

  // LDS 64KB: Xs[2][128][64]fp16 @0,16K; Ys[2][128][64] @32K,48K.
  // Mirror chunks (4 x 16x132 f32 = 33.8KB) alias post-loop.
  __shared__ __align__(16) char smem[65536];
  float* LDSf = (float*)smem;

  const int w = tid >> 6, lane = tid & 63;
  const int row0 = bi * 128, col0 = bj * 128;
  const int mrow = lane & 15;
  const int crow = (lane >> 4) * 4, ccol = lane & 15;
  f32x4 acc[8];
#pragma unroll
  for (int n = 0; n < 8; ++n) acc[n] = (f32x4){0.f, 0.f, 0.f, 0.f};

  // prologue: stage k-tile 0 into buffer 0
  stageXY(Gh, smem, smem + 32768, row0, col0, 0, w, lane);

  const int arow = w * 16 + mrow;            // A-frag local row
  const int xswA = (mrow & 7) << 4;          // read-side XOR (row&7)<<4
  for (int t = 0; t < 32; ++t) {
    __syncthreads();                         // buf[t&1] resident; prev reads done
    if (t < 31)
      stageXY(Gh, smem + ((t + 1) & 1) * 16384, smem + 32768 + ((t + 1) & 1) * 16384,
              row0, col0, (t + 1) * 64, w, lane);
    const char* Xb = smem + (t & 1) * 16384;
    const char* Yb = smem + 32768 + (t & 1) * 16384;
#pragma unroll
    for (int kk = 0; kk < 2; ++kk) {
      const int cb = kk * 64 + (lane >> 4) * 16;   // byte col of 16B frag
      half8 af = *(const half8*)(Xb + arow * 128 + (cb ^ xswA));
#pragma unroll
      for (int nt = 0; nt < 8; ++nt) {
        const int nrow = nt * 16 + mrow;
        half8 bf = *(const half8*)(Yb + nrow * 128 + (cb ^ ((nrow & 7) << 4)));
        acc[nt] = __builtin_amdgcn_mfma_f32_16x16x32_f16(af, bf, acc[nt], 0, 0, 0);
      }
    }
  }
  // ---- epilogue: direct write (always); mirror via LDS chunk (lower tiles) ----
  // C/D layout: col=lane&15, row=(lane>>4)*4+reg  [m89-verified]
  const float invn = 1.0f / 2048.0f;
  float vals[8][4];
#pragma unroll
  for (int nt = 0; nt < 8; ++nt) {
    const int gj = col0 + nt * 16 + ccol;
#pragma unroll
    for (int r = 0; r < 4; ++r) {
      const int gi = row0 + w * 16 + crow + r;
      float v = acc[nt][r] * invn + ((gi == gj) ? 1.0f : 0.0f);
      vals[nt][r] = v;
      M[(size_t)gi * 2048 + gj] = v;
    }
  }
  if (!diag) {
    __syncthreads();                         // staging reads done; LDSf safe
    for (int round = 0; round < 2; ++round) {
      if ((w >> 2) == round) {
        float* myc = LDSf + (w & 3) * (16 * 132);   // [16][132]
#pragma unroll
        for (int nt = 0; nt < 8; ++nt)
#pragma unroll
          for (int r = 0; r < 4; ++r)
            myc[(crow + r) * 132 + nt * 16 + ccol] = vals[nt][r];
        // same-wave LDS write->read (compiler inserts lgkmcnt waits)
        for (int u = 0; u < 32; ++u) {
          const int jj = u * 4 + (lane >> 4);       // tile col 0..127
          const int ii = lane & 15;                 // tile row-in-strip 0..15
          M[(size_t)(col0 + jj) * 2048 + row0 + w * 16 + ii] = myc[ii * 132 + jj];
        }
      }
      __syncthreads();
    }
  }
}

// ---- deterministic block-wide sum over 8 waves: bitwise-identical per block ----
__device__ __forceinline__ float block_sum8(float v, float* red) {
#pragma unroll
  for (int off = 32; off; off >>= 1) v += __shfl_down(v, off);
  if ((threadIdx.x & 63) == 0) red[threadIdx.x >> 6] = v;
  __syncthreads();
  float r = ((red[0] + red[1]) + (red[2] + red[3])) +
            ((red[4] + red[5]) + (red[6] + red[7]));
  __syncthreads();
  return r;
}

// ---- 5. Lanczos: single-phase epoch protocol, 128 x 512 — FROZEN core (R20) ----
// R20: ~4.2 us/iter exchange is the store->remote-observability floor.
// RULE 1 (R1/R6): cross-block data via agent-scope atomics only.
// RULE 2 (R1/R6/R8): beta^2 = ||z - alpha v||^2 DIRECT form only.
// RULE 3 (R16): no fixed-address staging reuse with plain cached loads.
// RULE 4 (R17): exactly ONE publish->consume phase per iteration.
// RULE 5 (R19/R20): exchange cost is per-phase visibility latency.
// RULE 6 (R14/R15): no serial dependent-load chains anywhere.
// R32: sparse term S + S^T + SS^T traversed in-kernel (chain-free).
__global__ __launch_bounds__(512) void lanczos_kernel(const float* __restrict__ M,
                                                      const unsigned* __restrict__ cntR,
                                                      const int* __restrict__ binRc,
                                                      const float* __restrict__ binRv,
                                                      const unsigned* __restrict__ cntC,
                                                      const int* __restrict__ binCr,
                                                      const float* __restrict__ binCv,
                                                      unsigned long long* __restrict__ Z0,
                                                      unsigned long long* __restrict__ Z1,
                                                      float* __restrict__ out) {
  const int tid = threadIdx.x, b = blockIdx.x;
  const int wave = tid >> 6, lane = tid & 63;
  __shared__ __align__(16) float Mlds[16 * 2048];  // 128 KB: this block's 16 rows
  __shared__ __align__(16) float VA[2048];
  __shared__ __align__(16) float VB[2048];
  __shared__ float red[8];
  __shared__ float al[LK + 2], b2[LK + 2];
  __shared__ float bnds[2], res[2];

  const float* Mblk = M + (size_t)b * 16 * 2048;
#pragma unroll
  for (int q = 0; q < 16; ++q)
    __builtin_amdgcn_global_load_lds(AS1C(Mblk + wave * 4096 + q * 256 + lane * 4),
                                     AS3(Mlds + wave * 4096 + q * 256), 16, 0, 0);

  // block-redundant init: v1 = hash / ||hash||  (identical in every block), v0 = 0
  float pv[4];
  float part = 0.f;
#pragma unroll
  for (int t = 0; t < 4; ++t) {
    int i = t * 512 + tid;
    unsigned u = (unsigned)i * 2654435761u;
    u ^= u >> 16; u *= 2246822519u; u ^= u >> 13;
    float rv = (float)(u >> 8) * (2.f / 16777216.f) - 1.f;
    pv[t] = rv;
    part += rv * rv;
  }
  float nrm = block_sum8(part, red);       // barriers inside drain Mlds staging
  float innm = rsqrtf(nrm);
#pragma unroll
  for (int t = 0; t < 4; ++t) {
    int i = t * 512 + tid;
    VA[i] = pv[t] * innm;
    VB[i] = 0.f;
  }
  __syncthreads();                         // Mlds fully staged; VA/VB ready

  // ---- R32: in-kernel sparse traversal for this block's rows ----
  for (int rr = 0; rr < 2; ++rr) {
    const int r = b * 16 + wave * 2 + rr;
    float* Mrow = Mlds + (wave * 2 + rr) * 2048;
    const unsigned nR = min(cntR[r], (unsigned)BINCAP);
    const unsigned nC = min(cntC[r], (unsigned)BINCAP);
    // lane e holds row-bin entry e (parallel loads; one dependent hop to cntC)
    int c_ = 0; float v_ = 0.f; unsigned n_ = 0;
    if (lane < nR) {
      c_ = binRc[r * BINCAP + lane];
      v_ = binRv[r * BINCAP + lane];
      n_ = min(cntC[c_], (unsigned)BINCAP);
    }
    // S: M[r, c_e] += v_e
    if (lane < nR) atomicAdd(&Mrow[c_], v_);
    // S^T: column bin r -> M[r, j_e] += v_e
    if (lane < nC)
      atomicAdd(&Mrow[binCr[r * BINCAP + lane]], binCv[r * BINCAP + lane]);
    // SS^T: group g (16 lanes) expands entry e = g, g+4, ... via shfl-broadcast
    const unsigned g = lane >> 4, p0 = lane & 15;
    for (unsigned e = g; e < nR; e += 4) {
      const int c = __shfl(c_, (int)e);
      const float v = __shfl(v_, (int)e);
      const unsigned n2 = __shfl(n_, (int)e);
      for (unsigned p = p0; p < n2; p += 16)
        atomicAdd(&Mrow[binCr[c * BINCAP + p]], v * binCv[c * BINCAP + p]);
    }
  }
  __syncthreads();                         // sparse apply complete

  float* Vcur = VA;
  float* Vprev = VB;
  float beta_prev = 0.f;

  for (int j = 1; j <= LK; ++j) {
    unsigned long long* Z = (j & 1) ? Z0 : Z1;
#pragma unroll
    for (int rr = 0; rr < 2; ++rr) {
      const int r = b * 16 + wave * 2 + rr;
      const float4* Mr = (const float4*)(Mlds + (wave * 2 + rr) * 2048);
      float s = 0.f;
#pragma unroll
      for (int t = 0; t < 8; ++t) {
        int idx = t * 64 + lane;
        float4 m4 = Mr[idx];
        float4 v4 = ((const float4*)Vcur)[idx];
        s += m4.x * v4.x + m4.y * v4.y + m4.z * v4.z + m4.w * v4.w;
      }
#pragma unroll
      for (int off = 32; off; off >>= 1) s += __shfl_down(s, off);
      if (lane == 0) {
        float zv = s - beta_prev * Vprev[r];
        unsigned long long pk = ((unsigned long long)(unsigned)j << 32) |
                                (unsigned long long)(unsigned)__float_as_uint(zv);
        __hip_atomic_store(&Z[r], pk, __ATOMIC_RELAXED, AGENT);
      }
    }

    // hoist own v-slice reads (LDS) ahead of the poll — free overlap
    float va[4];
#pragma unroll
    for (int t = 0; t < 4; ++t) va[t] = Vcur[t * 512 + tid];

    unsigned long long w4[4];
    int rounds = 0;
    for (;;) {
      bool ok = true;
#pragma unroll
      for (int t = 0; t < 4; ++t) {
        w4[t] = __hip_atomic_load(&Z[t * 512 + tid], __ATOMIC_RELAXED, AGENT);
        ok &= ((unsigned)(w4[t] >> 32) == (unsigned)j);
      }
      if (ok) break;
      if (rounds == 1)      __builtin_amdgcn_s_sleep(1);   //  64 clk
      else if (rounds == 2) __builtin_amdgcn_s_sleep(2);   // 128 clk
      else if (rounds >= 3) __builtin_amdgcn_s_sleep(8);   // 512 clk
      ++rounds;
    }
    float za[4];
    float pa = 0.f;
#pragma unroll
    for (int t = 0; t < 4; ++t) {
      za[t] = __uint_as_float((unsigned)w4[t]);
      pa += za[t] * va[t];
    }
    float alpha = block_sum8(pa, red);
    float pb = 0.f;
#pragma unroll
    for (int t = 0; t < 4; ++t) {
      float rsd = za[t] - alpha * va[t];
      pb += rsd * rsd;
    }
    float beta2 = block_sum8(pb, red);
    float beta = sqrtf(fmaxf(beta2, 1e-30f));
    float invb = 1.f / beta;
    if (tid == 0) { al[j] = alpha; b2[j] = beta2; }
#pragma unroll
    for (int t = 0; t < 4; ++t) {
      int i = t * 512 + tid;
      Vprev[i] = (za[t] - alpha * va[t]) * invb;
    }
    float* tmp = Vprev; Vprev = Vcur; Vcur = tmp;
    beta_prev = beta;
    __syncthreads();
  }

  // ---- extreme eigenvalues of T via Sturm bisection (block 0) ----
  if (b == 0) {
    if (tid == 0) {                                  // Gershgorin bounds on T
      float lo = 1e30f, hi = -1e30f;
      for (int i = 1; i <= LK; ++i) {
        float bl = (i > 1) ? sqrtf(b2[i - 1]) : 0.f;
        float br = (i < LK) ? sqrtf(b2[i]) : 0.f;
        lo = fminf(lo, al[i] - bl - br);
        hi = fmaxf(hi, al[i] + bl + br);
      }
      bnds[0] = lo; bnds[1] = hi;
    }
    __syncthreads();
    if (wave < 2) {                 // wave 0 -> lambda_min, wave 1 -> lambda_max
      const int tcount = (wave == 0) ? 1 : LK;
      float lo = bnds[0], hi = bnds[1];
      for (int round = 0; round < 4; ++round) {
        float x = lo + (hi - lo) * (float)(lane + 1) * (1.f / 65.f);
        int cnt = 0;                                 // #eigs of T below x
        float d = al[1] - x;
        if (fabsf(d) < 1e-25f) d = -1e-25f;
        if (d < 0.f) cnt++;
        for (int i = 2; i <= LK; ++i) {
          d = (al[i] - x) - b2[i - 1] / d;
          if (fabsf(d) < 1e-25f) d = -1e-25f;
          if (d < 0.f) cnt++;
        }
        bool ab = (cnt >= tcount);                   // x is above the target eig
        float cand_hi = ab ? x : hi;
        float cand_lo = ab ? lo : x;
#pragma unroll
        for (int off = 32; off; off >>= 1) {
          cand_hi = fminf(cand_hi, __shfl_down(cand_hi, off));
          cand_lo = fmaxf(cand_lo, __shfl_down(cand_lo, off));
        }
        cand_hi = __shfl(cand_hi, 0);
        cand_lo = __shfl(cand_lo, 0);
        hi = cand_hi;
        lo = fminf(cand_lo, hi);
      }
      if (lane == 0) res[wave] = 0.5f * (lo + hi);
    }
    __syncthreads();
    if (tid == 0) {
      float lmin = fmaxf(res[0], 1e-12f);
      float lmax = fmaxf(res[1], 1e-12f);
      out[0] = logf(lmax) - logf(lmin);
    }
  }
}

extern "C" void kernel_launch(void* const* d_in, const int* in_sizes, int n_in,
                              void* d_out, int out_size, void* d_ws, size_t ws_size,
                              hipStream_t stream) {
  const float* pred = (const float*)d_in[0];
  const float* scal = (const float*)d_in[1];
  const float* W    = (const float*)d_in[2];
  const int*   rows = (const int*)d_in[3];
  const int*   cols = (const int*)d_in[4];
  float* out = (float*)d_out;

  // workspace layout (peak ~34.2 MB):
  //  [0,8MB)   : Hf fp16
  //  [8,16MB)  : Gh fp16 (G = L*Wh)
  //  [16,32MB) : M fp32
  //  [32MB,..) : cntR 8KB | cntC 8KB | binRc 512KB | binRv 512KB |
  //              binCr 512KB | binCv 512KB | Z0 16KB | Z1 16KB
  char* ws = (char*)d_ws;
  const size_t MB = 1024 * 1024;
  unsigned short* Hf = (unsigned short*)(ws);
  unsigned short* Gh = (unsigned short*)(ws + 8 * MB);
  float* M = (float*)(ws + 16 * MB);
  char* ctrl = ws + 32 * MB;
  unsigned* cntR = (unsigned*)(ctrl);
  unsigned* cntC = (unsigned*)(ctrl + 8192);
  int*      binRc = (int*)(ctrl + 16384);
  float*    binRv = (float*)(ctrl + 16384 + 524288);
  int*      binCr = (int*)(ctrl + 16384 + 2 * 524288);
  float*    binCv = (float*)(ctrl + 16384 + 3 * 524288);
  unsigned long long* Z0 = (unsigned long long*)(ctrl + 16384 + 4 * 524288);
  unsigned long long* Z1 = (unsigned long long*)(ctrl + 16384 + 4 * 524288 + 16384);

  convert_kernel<<<4096, 256, 0, stream>>>(W, Hf, cntR, cntC);
  fill_kernel<<<NNZ / 256, 256, 0, stream>>>(pred, scal, rows, cols,
                                             cntR, binRc, binRv, cntC, binCr, binCv);
  gatherG_kernel<<<2048, 256, 0, stream>>>(cntR, binRc, binRv, Hf, Gh);  // G = L*Wh
  gemmM_kernel<<<136, 512, 0, stream>>>(Gh, M);    // M = GG^T/N + I (128x128 tiles)
  lanczos_kernel<<<NBL, 512, 0, stream>>>(M, cntR, binRc, binRv,
                                          cntC, binCr, binCv, Z0, Z1, out);
}